// Round 12
// baseline (757.637 us; speedup 1.0000x reference)
//
#include <hip/hip_runtime.h>
#include <stdint.h>

#define NP 2048
#define KNN 40
#define CAP 128          // candidate buffer per row (2 slots of 64, int — proven type)

__device__ __forceinline__ unsigned fOrd(float f) {
    unsigned u = __float_as_uint(f);
    return u ^ ((unsigned)((int)u >> 31) | 0x80000000u);
}
__device__ __forceinline__ unsigned long long dOrd(double d) {
    unsigned long long u = (unsigned long long)__double_as_longlong(d);
    return u ^ (((unsigned long long)((long long)u >> 63)) | 0x8000000000000000ull);
}

// ---------------------------------------------------------------------------
// prep: per point: xx = sum x^2 (fp32), p[o] = Wd[o,:]·x, r[o] = (Wc-Wd)[o,:]·x,
// XT[b][n][0..CP) = x (point-contiguous, zero-padded) + fp64 norm at offset CP
// (sequential c-order — must match refine's usage). Used only for block 1.
// ---------------------------------------------------------------------------
template<int C, int CP, int CPX>
__global__ void prep_kernel(const float* __restrict__ X, long bstride,
                            const float* __restrict__ W,
                            float* __restrict__ p, float* __restrict__ r,
                            float* __restrict__ xx, float* __restrict__ XT) {
    __shared__ float wdT[C][32];
    __shared__ float wrT[C][32];
    int tid = threadIdx.x;
    for (int i = tid; i < 32 * C; i += 256) {
        int o = i / C, c = i - o * C;
        float wd = W[o * 2 * C + c];
        float wc = W[o * 2 * C + C + c];
        wdT[c][o] = wd;
        wrT[c][o] = wc - wd;
    }
    __syncthreads();
    int lane = tid & 63;
    int o = lane & 31;
    int h = lane >> 5;
    int wv = tid >> 6;
    int flat = blockIdx.x * 8 + wv * 2 + h;   // 2048 wgs * 8 points = B*N
    int b = flat >> 11, n = flat & 2047;
    const float* Xb = X + (long)b * bstride + n;
    float pacc = 0.f, racc = 0.f, xxa = 0.f, xto = 0.f;
    double xxd = 0.0;
#pragma unroll
    for (int c = 0; c < C; c++) {
        float xv = Xb[(long)c * NP];
        pacc = fmaf(wdT[c][o], xv, pacc);
        racc = fmaf(wrT[c][o], xv, racc);
        xxa += xv * xv;
        xxd += (double)xv * (double)xv;       // sequential c order (refine-consistent)
        if (c == o) xto = xv;
    }
    long base = ((long)b * NP + n) * 32 + o;
    p[base] = pacc;
    r[base] = racc;
    long rowb = ((long)b * NP + n) * CPX;
    if (o < CP) XT[rowb + o] = (o < C) ? xto : 0.f;
    if (o == 0) {
        xx[b * NP + n] = xxa;
        *reinterpret_cast<double*>(&XT[rowb + CP]) = xxd;
    }
}

// ---------------------------------------------------------------------------
// knn R26: 4 ROWS PER WAVE (was 2). knn C9 == knn C32 == 127us across R7-R11
// proves the wall is the C-independent select machinery's serial chains at
// VALUBusy 44% (56% idle issue). 4 independent chains per wave fill the
// idle slots on pass-1 steps / bitonic stages / refine / gather; staging
// per row halves. Per-row math, ballot structure, sort network, tie
// semantics are byte-identical (rows 0..3 instead of A/B, static indexing).
// VGPR gate: keys = 64 regs + ~overhead 20-40 -> must stay <=128 (else
// waves/SIMD < 4 and the 2-blocks/CU grid under-fills). Spill gate:
// WRITE_SIZE must stay ~4.3MB.
// wg = 512 = 8 waves; each wave owns 4 rows; 512 wgs (64 per batch).
// ---------------------------------------------------------------------------
template<int C, int CP, int CPX>
__global__ __launch_bounds__(512, 2)
void knn_kernel(const float* __restrict__ X, long bstride,
                const float* __restrict__ p, const float* __restrict__ r,
                const float* __restrict__ xx, const float* __restrict__ XT,
                float* __restrict__ mmax, float* __restrict__ mmin,
                float* __restrict__ sums) {
    // union region: xt[2][C*128] (distance) OR cand[32][CAP]+sel[32][KNN]
    constexpr int XT_FLOATS = 2 * C * 128;
    constexpr int CS_FLOATS = 32 * CAP + 32 * KNN;
    constexpr int UNI_FLOATS = (XT_FLOATS > CS_FLOATS) ? XT_FLOATS : CS_FLOATS;
    __shared__ __align__(16) float uni[UNI_FLOATS];
    __shared__ __align__(16) float xxt[256];
    __shared__ __align__(16) float qld[8][CP][4];  // [wave][c][row0..3]
    __shared__ float S1loc[32], S2loc[32];
    int* candb = (int*)uni;               // valid after post-distance barrier
    int* selb  = (int*)uni + 32 * CAP;
    int tid = threadIdx.x;
    if (tid < 32) { S1loc[tid] = 0.f; S2loc[tid] = 0.f; }
    int lane = tid & 63;
    int wv = tid >> 6;                    // 0..7
    int half = lane >> 5;                 // which of the 2 staged tiles
    int l32 = lane & 31;
    int b = blockIdx.x >> 6;              // 64 wgs per batch
    int n0 = (blockIdx.x & 63) * 32;
    int nn0 = n0 + wv * 4, nn1 = nn0 + 1, nn2 = nn0 + 2, nn3 = nn0 + 3;
    int r0 = wv * 4, r1 = r0 + 1, r2 = r0 + 2, r3 = r0 + 3;   // 0..31
    const float* Xb = X + (long)b * bstride;
    const float* XTb = XT + (long)b * NP * CPX;
    long bNP = (long)b * NP;

    // queries -> LDS (wave-private rows; barrier below covers visibility)
    if (lane < CP) {
        qld[wv][lane][0] = XTb[(long)nn0 * CPX + lane];
        qld[wv][lane][1] = XTb[(long)nn1 * CPX + lane];
        qld[wv][lane][2] = XTb[(long)nn2 * CPX + lane];
        qld[wv][lane][3] = XTb[(long)nn3 * CPX + lane];
    }
    float xxn0 = xx[bNP + nn0];
    float xxn1 = xx[bNP + nn1];
    float xxn2 = xx[bNP + nn2];
    float xxn3 = xx[bNP + nn3];

    unsigned u0[16], u1[16], u2[16], u3[16];  // 16-bit keys, 2/reg per row
    for (int t2 = 0; t2 < 8; t2++) {
        __syncthreads();
        // stage tiles 2*t2 (->half 0) and 2*t2+1 (->half 1); R10 pattern
        for (int i = tid; i < C * 64; i += 512) {
            int c = i >> 6, g = i & 63;
            int tt = g >> 5, gg = g & 31;
            *(float4*)&uni[tt * (C * 128) + c * 128 + gg * 4] =
                *(const float4*)&Xb[(long)c * NP + (t2 * 2 + tt) * 128 + gg * 4];
        }
        if (tid < 256) xxt[tid] = xx[bNP + t2 * 256 + tid];
        __syncthreads();
        const float* xth = uni + half * (C * 128);
        float4 acc0 = make_float4(0.f, 0.f, 0.f, 0.f);
        float4 acc1 = make_float4(0.f, 0.f, 0.f, 0.f);
        float4 acc2 = make_float4(0.f, 0.f, 0.f, 0.f);
        float4 acc3 = make_float4(0.f, 0.f, 0.f, 0.f);
#pragma unroll
        for (int c = 0; c < C; c++) {
            float4 q = *(const float4*)&qld[wv][c][0];       // b128 broadcast
            float4 xv = *(const float4*)&xth[c * 128 + 4 * l32]; // ONE b128/c
            acc0.x = fmaf(q.x, xv.x, acc0.x); acc0.y = fmaf(q.x, xv.y, acc0.y);
            acc0.z = fmaf(q.x, xv.z, acc0.z); acc0.w = fmaf(q.x, xv.w, acc0.w);
            acc1.x = fmaf(q.y, xv.x, acc1.x); acc1.y = fmaf(q.y, xv.y, acc1.y);
            acc1.z = fmaf(q.y, xv.z, acc1.z); acc1.w = fmaf(q.y, xv.w, acc1.w);
            acc2.x = fmaf(q.z, xv.x, acc2.x); acc2.y = fmaf(q.z, xv.y, acc2.y);
            acc2.z = fmaf(q.z, xv.z, acc2.z); acc2.w = fmaf(q.z, xv.w, acc2.w);
            acc3.x = fmaf(q.w, xv.x, acc3.x); acc3.y = fmaf(q.w, xv.y, acc3.y);
            acc3.z = fmaf(q.w, xv.z, acc3.z); acc3.w = fmaf(q.w, xv.w, acc3.w);
        }
        float4 xm = *(const float4*)&xxt[half * 128 + 4 * l32];
#define KEYPACK(i) { \
        unsigned a0_ = fOrd((xxn##i - 2.0f * acc##i.x) + xm.x) >> 16; \
        unsigned a1_ = fOrd((xxn##i - 2.0f * acc##i.y) + xm.y) >> 16; \
        unsigned a2_ = fOrd((xxn##i - 2.0f * acc##i.z) + xm.z) >> 16; \
        unsigned a3_ = fOrd((xxn##i - 2.0f * acc##i.w) + xm.w) >> 16; \
        u##i[2 * t2]     = (a1_ << 16) | a0_; \
        u##i[2 * t2 + 1] = (a3_ << 16) | a2_; }
        KEYPACK(0) KEYPACK(1) KEYPACK(2) KEYPACK(3)
#undef KEYPACK
    }
    // lifetime switch: all waves done reading xt before cand/sel writes
    __syncthreads();

    unsigned long long lmlt = (1ull << lane) - 1ull;

    // hoist f64 self-norms (independent global loads, hide under select)
    double xxd0 = *reinterpret_cast<const double*>(&XTb[(long)nn0 * CPX + CP]);
    double xxd1 = *reinterpret_cast<const double*>(&XTb[(long)nn1 * CPX + CP]);
    double xxd2 = *reinterpret_cast<const double*>(&XTb[(long)nn2 * CPX + CP]);
    double xxd3 = *reinterpret_cast<const double*>(&XTb[(long)nn3 * CPX + CP]);

    // --- pass 1 select, 4 rows: fixed 16-step bitwise rank-40 select ---
    unsigned v0 = 0u, v1 = 0u, v2 = 0u, v3 = 0u;
    for (int bit = 15; bit >= 0; bit--) {
        unsigned low = (1u << bit) - 1u;
        unsigned t0_ = v0 | low, t1_ = v1 | low, t2_ = v2 | low, t3_ = v3 | low;
        int c0_ = 0, c1_ = 0, c2_ = 0, c3_ = 0;
#pragma unroll
        for (int t = 0; t < 16; t++) {
            c0_ += __popcll(__ballot((u0[t] & 0xFFFFu) <= t0_));
            c0_ += __popcll(__ballot((u0[t] >> 16) <= t0_));
            c1_ += __popcll(__ballot((u1[t] & 0xFFFFu) <= t1_));
            c1_ += __popcll(__ballot((u1[t] >> 16) <= t1_));
            c2_ += __popcll(__ballot((u2[t] & 0xFFFFu) <= t2_));
            c2_ += __popcll(__ballot((u2[t] >> 16) <= t2_));
            c3_ += __popcll(__ballot((u3[t] & 0xFFFFu) <= t3_));
            c3_ += __popcll(__ballot((u3[t] >> 16) <= t3_));
        }
        if (c0_ < KNN) v0 |= (1u << bit);
        if (c1_ < KNN) v1 |= (1u << bit);
        if (c2_ < KNN) v2 |= (1u << bit);
        if (c3_ < KNN) v3 |= (1u << bit);
    }
    unsigned thr0 = (v0 > 0xFFFEu) ? 0xFFFFu : v0 + 1u;   // +1 bucket (proven)
    unsigned thr1 = (v1 > 0xFFFEu) ? 0xFFFFu : v1 + 1u;
    unsigned thr2 = (v2 > 0xFFFEu) ? 0xFFFFu : v2 + 1u;
    unsigned thr3 = (v3 > 0xFFFEu) ? 0xFFFFu : v3 + 1u;

    // --- candidate lists, 4 rows (m = (kk>>1)*256 + half*128 + 4*l32 + (kk&1)*2 + hh) ---
    int base0 = 0, base1 = 0, base2 = 0, base3 = 0;
#pragma unroll
    for (int kk = 0; kk < 16; kk++) {
#pragma unroll
        for (int hh = 0; hh < 2; hh++) {
            int idx = (kk >> 1) * 256 + half * 128 + 4 * l32 + (kk & 1) * 2 + hh;
#define COMPACT(i) { \
            unsigned k_ = hh ? (u##i[kk] >> 16) : (u##i[kk] & 0xFFFFu); \
            bool p_ = (k_ <= thr##i); \
            unsigned long long mk_ = __ballot(p_); \
            if (p_) { \
                int pos = base##i + __popcll(mk_ & lmlt); \
                if (pos < CAP) candb[r##i * CAP + pos] = idx; \
            } \
            base##i += __popcll(mk_); }
            COMPACT(0) COMPACT(1) COMPACT(2) COMPACT(3)
#undef COMPACT
        }
    }
    int cnt0 = base0 < CAP ? base0 : CAP;
    int cnt1 = base1 < CAP ? base1 : CAP;
    int cnt2 = base2 < CAP ? base2 : CAP;
    int cnt3 = base3 < CAP ? base3 : CAP;

    // --- refine candidates in float64, 4 rows (exact order preserved) ---
    unsigned long long key0[CAP / 64], key1[CAP / 64], key2[CAP / 64], key3[CAP / 64];
    int mix0[CAP / 64], mix1[CAP / 64], mix2[CAP / 64], mix3[CAP / 64];
#pragma unroll
    for (int s3 = 0; s3 < CAP / 64; s3++) {
        int slot = s3 * 64 + lane;
        key0[s3] = ~0ull; mix0[s3] = 0;
        key1[s3] = ~0ull; mix1[s3] = 0;
        key2[s3] = ~0ull; mix2[s3] = 0;
        key3[s3] = ~0ull; mix3[s3] = 0;
#define REFINE(i) \
        if (slot < cnt##i) { \
            int m = candb[r##i * CAP + slot] & (NP - 1); \
            mix##i[s3] = m; \
            const float* xmp = XTb + (long)m * CPX; \
            double inner = 0.0; \
            _Pragma("unroll") \
            for (int g = 0; g < CP / 4; g++) { \
                float4 v = *(const float4*)&xmp[g * 4]; \
                inner += (double)qld[wv][g * 4 + 0][i] * (double)v.x; \
                inner += (double)qld[wv][g * 4 + 1][i] * (double)v.y; \
                inner += (double)qld[wv][g * 4 + 2][i] * (double)v.z; \
                inner += (double)qld[wv][g * 4 + 3][i] * (double)v.w; \
            } \
            double xxm = *reinterpret_cast<const double*>(&xmp[CP]); \
            double dd = (xxd##i - 2.0 * inner) + xxm; \
            key##i[s3] = dOrd(dd); \
        }
        REFINE(0) REFINE(1) REFINE(2) REFINE(3)
#undef REFINE
    }

    // --- R20: rank select via in-register bitonic sort by (key, idx) ---
    auto cex = [](unsigned long long& k, int& i, const int S, const bool keepmin) {
        unsigned long long pk = __shfl_xor(k, S);
        int pi = __shfl_xor(i, S);
        bool less = (k < pk) || (k == pk && i < pi);
        bool tp = (less != keepmin);
        k = tp ? pk : k;
        i = tp ? pi : i;
    };
    if (cnt0 <= 64 && cnt1 <= 64 && cnt2 <= 64 && cnt3 <= 64) {
        // 64-element ascending bitonic sort, slot0 only (21 stages, 4 chains)
#pragma unroll
        for (int kk2 = 1; kk2 <= 6; kk2++) {
            const int K = 1 << kk2;
#pragma unroll
            for (int ss = kk2 - 1; ss >= 0; ss--) {
                const int S = 1 << ss;
                bool asc0 = (K == 64) ? true : ((lane & K) == 0);
                bool km0 = ((lane & S) == 0) == asc0;
                cex(key0[0], mix0[0], S, km0);
                cex(key1[0], mix1[0], S, km0);
                cex(key2[0], mix2[0], S, km0);
                cex(key3[0], mix3[0], S, km0);
            }
        }
    } else {
        // 128-element ascending bitonic sort, 2 slots/lane (elem j = s3*64+lane)
#pragma unroll
        for (int kk2 = 1; kk2 <= 6; kk2++) {
            const int K = 1 << kk2;
#pragma unroll
            for (int ss = kk2 - 1; ss >= 0; ss--) {
                const int S = 1 << ss;
                bool ascL = (lane & K) == 0;
                bool asc0 = (K == 64) ? true  : ascL;   // j&64 = 0 for slot0
                bool asc1 = (K == 64) ? false : ascL;   // j&64 = 64 for slot1
                bool km0 = ((lane & S) == 0) == asc0;
                bool km1 = ((lane & S) == 0) == asc1;
                cex(key0[0], mix0[0], S, km0); cex(key0[1], mix0[1], S, km1);
                cex(key1[0], mix1[0], S, km0); cex(key1[1], mix1[1], S, km1);
                cex(key2[0], mix2[0], S, km0); cex(key2[1], mix2[1], S, km1);
                cex(key3[0], mix3[0], S, km0); cex(key3[1], mix3[1], S, km1);
            }
        }
        // K=128 level. s=64: local exchange between slots (ascending: e0=min)
#define LOCEX(i) { \
        bool l_ = (key##i[0] < key##i[1]) || (key##i[0] == key##i[1] && mix##i[0] < mix##i[1]); \
        unsigned long long tk_ = key##i[0]; int ti_ = mix##i[0]; \
        key##i[0] = l_ ? key##i[0] : key##i[1];  mix##i[0] = l_ ? mix##i[0] : mix##i[1]; \
        key##i[1] = l_ ? key##i[1] : tk_;        mix##i[1] = l_ ? mix##i[1] : ti_; }
        LOCEX(0) LOCEX(1) LOCEX(2) LOCEX(3)
#undef LOCEX
        // s = 32..1, ascending everywhere (j&128 == 0)
#pragma unroll
        for (int ss = 5; ss >= 0; ss--) {
            const int S = 1 << ss;
            bool km = ((lane & S) == 0);
            cex(key0[0], mix0[0], S, km); cex(key0[1], mix0[1], S, km);
            cex(key1[0], mix1[0], S, km); cex(key1[1], mix1[1], S, km);
            cex(key2[0], mix2[0], S, km); cex(key2[1], mix2[1], S, km);
            cex(key3[0], mix3[0], S, km); cex(key3[1], mix3[1], S, km);
        }
    }
    // ranks 0..63 now live in slot0 by lane; emit the 40 smallest (key,idx).
    // Emission writes ALL 40 slots unconditionally -> sel needs no init.
    if (lane < KNN) {
        selb[r0 * KNN + lane] = mix0[0];
        selb[r1 * KNN + lane] = mix1[0];
        selb[r2 * KNN + lane] = mix2[0];
        selb[r3 * KNN + lane] = mix3[0];
    }

    // --- fused gather-reduce over the selected 40, 4 rows ---
    {
        int o = lane & 31, h = lane >> 5;
        float s10 = 0.f, s20 = 0.f, s11 = 0.f, s21 = 0.f;
        float s12 = 0.f, s22 = 0.f, s13 = 0.f, s23 = 0.f;
        float mx0 = -__builtin_inff(), mn0 = __builtin_inff();
        float mx1 = -__builtin_inff(), mn1 = __builtin_inff();
        float mx2 = -__builtin_inff(), mn2 = __builtin_inff();
        float mx3 = -__builtin_inff(), mn3 = __builtin_inff();
        const float* pb = p + bNP * 32 + o;
        for (int k = h * 20; k < h * 20 + 20; k++) {
            int m0_ = selb[r0 * KNN + k] & (NP - 1);   // defensive mask
            int m1_ = selb[r1 * KNN + k] & (NP - 1);
            int m2_ = selb[r2 * KNN + k] & (NP - 1);
            int m3_ = selb[r3 * KNN + k] & (NP - 1);
            float pv0 = pb[(long)m0_ * 32];
            float pv1 = pb[(long)m1_ * 32];
            float pv2 = pb[(long)m2_ * 32];
            float pv3 = pb[(long)m3_ * 32];
            s10 += pv0; s20 = fmaf(pv0, pv0, s20);
            mx0 = fmaxf(mx0, pv0); mn0 = fminf(mn0, pv0);
            s11 += pv1; s21 = fmaf(pv1, pv1, s21);
            mx1 = fmaxf(mx1, pv1); mn1 = fminf(mn1, pv1);
            s12 += pv2; s22 = fmaf(pv2, pv2, s22);
            mx2 = fmaxf(mx2, pv2); mn2 = fminf(mn2, pv2);
            s13 += pv3; s23 = fmaf(pv3, pv3, s23);
            mx3 = fmaxf(mx3, pv3); mn3 = fminf(mn3, pv3);
        }
        s10 += __shfl_xor(s10, 32); s20 += __shfl_xor(s20, 32);
        mx0 = fmaxf(mx0, __shfl_xor(mx0, 32)); mn0 = fminf(mn0, __shfl_xor(mn0, 32));
        s11 += __shfl_xor(s11, 32); s21 += __shfl_xor(s21, 32);
        mx1 = fmaxf(mx1, __shfl_xor(mx1, 32)); mn1 = fminf(mn1, __shfl_xor(mn1, 32));
        s12 += __shfl_xor(s12, 32); s22 += __shfl_xor(s22, 32);
        mx2 = fmaxf(mx2, __shfl_xor(mx2, 32)); mn2 = fminf(mn2, __shfl_xor(mn2, 32));
        s13 += __shfl_xor(s13, 32); s23 += __shfl_xor(s23, 32);
        mx3 = fmaxf(mx3, __shfl_xor(mx3, 32)); mn3 = fminf(mn3, __shfl_xor(mn3, 32));
        if (h == 0) {
#define FINROW(i, s1v, s2v, mxv, mnv) { \
            long bse_ = (bNP + nn##i) * 32 + o; \
            float q_ = r[bse_]; \
            mmax[bse_] = mxv + q_; \
            mmin[bse_] = mnv + q_; \
            atomicAdd(&S1loc[o], s1v + 40.f * q_); \
            atomicAdd(&S2loc[o], fmaf(2.f * q_, s1v, fmaf(40.f * q_, q_, s2v))); }
            FINROW(0, s10, s20, mx0, mn0)
            FINROW(1, s11, s21, mx1, mn1)
            FINROW(2, s12, s22, mx2, mn2)
            FINROW(3, s13, s23, mx3, mn3)
#undef FINROW
        }
    }
    __syncthreads();
    if (tid < 32) {
        atomicAdd(&sums[tid], S1loc[tid]);
        atomicAdd(&sums[32 + tid], S2loc[tid]);
    }
}

// ---------------------------------------------------------------------------
// fp_kernel (R25): fused finish(k-1) + prep(k), C=32 blocks only.
// ---------------------------------------------------------------------------
__global__ __launch_bounds__(256)
void fp_kernel(const float* __restrict__ mmax, const float* __restrict__ mmin,
               const float* __restrict__ sums_prev,
               const float* __restrict__ g, const float* __restrict__ be,
               const float* __restrict__ resid, float* __restrict__ outb,
               const float* __restrict__ W,
               float* __restrict__ p, float* __restrict__ r,
               float* __restrict__ xx, float* __restrict__ XT) {
    constexpr int C = 32, CP = 32, CPX = 36;
    __shared__ float wdT[C][32];
    __shared__ float wrT[C][32];
    __shared__ float yb[8][33];               // +1 pad: phase-2 bank spread
    int tid = threadIdx.x;
    for (int i = tid; i < 32 * C; i += 256) {
        int o = i / C, c = i - o * C;
        float wd = W[o * 2 * C + c];
        float wc = W[o * 2 * C + C + c];
        wdT[c][o] = wd;
        wrT[c][o] = wc - wd;
    }
    int flat0 = blockIdx.x * 8;               // 8 points per block
    int b = flat0 >> 11;
    int nb = flat0 & 2047;
    long bNP = (long)b * NP;
    const float cntf = 655360.0f;             // B*N*K
    {   // phase 1: c-fast — mmax/mmin reads fully coalesced
        int pi = tid >> 5, c = tid & 31;
        int n = nb + pi;
        float mean = sums_prev[c] / cntf;
        float var = sums_prev[32 + c] / cntf - mean * mean;
        float sc = g[c] / sqrtf(var + 1e-5f);
        float sh = be[c] - mean * sc;
        long bse = (bNP + n) * 32 + c;
        float v = (sc >= 0.f) ? mmax[bse] : mmin[bse];
        float y = sc * v + sh;
        y = (y >= 0.f) ? y : 0.2f * y;        // leaky BEFORE resid (ref order)
        yb[pi][c] = y;
    }
    __syncthreads();
    {   // phase 2: n-fast — resid/outb in contiguous 32B chunks per channel
        int c = tid >> 3, ni = tid & 7;
        int n = nb + ni;
        long ob = ((long)b * 128 + c) * NP + n;
        float y = yb[ni][c];
        if (resid) y += resid[ob];
        outb[ob] = y;                         // next knn stages X from here
        yb[ni][c] = y;
    }
    __syncthreads();
    // phase 3: prep from LDS y (identical math/order to prep_kernel)
    int lane = tid & 63;
    int o = lane & 31;
    int h = lane >> 5;
    int wv = tid >> 6;
    int pt = wv * 2 + h;
    int n = nb + pt;
    float pacc = 0.f, racc = 0.f, xxa = 0.f, xto = 0.f;
    double xxd = 0.0;
#pragma unroll
    for (int c = 0; c < C; c++) {
        float xv = yb[pt][c];
        pacc = fmaf(wdT[c][o], xv, pacc);
        racc = fmaf(wrT[c][o], xv, racc);
        xxa += xv * xv;
        xxd += (double)xv * (double)xv;       // sequential c order (refine-consistent)
        if (c == o) xto = xv;
    }
    long base = (bNP + n) * 32 + o;
    p[base] = pacc;
    r[base] = racc;
    long rowb = (bNP + n) * CPX;
    XT[rowb + o] = xto;                       // o < CP(=32) always; o<C always
    if (o == 0) {
        xx[bNP + n] = xxa;
        *reinterpret_cast<double*>(&XT[rowb + CP]) = xxd;
    }
}

// ---------------------------------------------------------------------------
// final in-place GEMM on d_out with finish4 FUSED for channels 96..128
// ---------------------------------------------------------------------------
__global__ void final_gemm(const float* __restrict__ W5, float* __restrict__ out,
                           const float* __restrict__ mmax, const float* __restrict__ mmin,
                           const float* __restrict__ sums4,
                           const float* __restrict__ g4, const float* __restrict__ be4) {
    __shared__ __align__(16) float catL[128][32];
    int b = blockIdx.x >> 6;
    int n0 = (blockIdx.x & 63) * 32;
    int tid = threadIdx.x;
    const float cntf = 655360.0f;
    long bNP = (long)b * NP;
    for (int i = tid; i < 128 * 32; i += 256) {
        int c = i >> 5, nn = i & 31;
        float val;
        if (c < 96) {
            val = out[((long)b * 128 + c) * NP + n0 + nn];
        } else {
            int o = c - 96;                    // inline finish4
            float mean = sums4[o] / cntf;
            float var = sums4[32 + o] / cntf - mean * mean;
            float sc = g4[o] / sqrtf(var + 1e-5f);
            float sh = be4[o] - mean * sc;
            long bse = (bNP + n0 + nn) * 32 + o;
            float v = (sc >= 0.f) ? mmax[bse] : mmin[bse];
            float y = sc * v + sh;
            y = (y >= 0.f) ? y : 0.2f * y;
            y += out[((long)b * 128 + 64 + o) * NP + n0 + nn];   // resid = x3
            val = y;
        }
        catL[c][nn] = val;
    }
    __syncthreads();
    int og = tid >> 3, ng = tid & 7;
    int o0 = og * 4, nl = ng * 4;
    float acc[4][4] = {};
    for (int c = 0; c < 128; c++) {
        float4 cv = *(const float4*)&catL[c][nl];
#pragma unroll
        for (int i = 0; i < 4; i++) {
            float w = W5[(o0 + i) * 128 + c];
            acc[i][0] = fmaf(w, cv.x, acc[i][0]);
            acc[i][1] = fmaf(w, cv.y, acc[i][1]);
            acc[i][2] = fmaf(w, cv.z, acc[i][2]);
            acc[i][3] = fmaf(w, cv.w, acc[i][3]);
        }
    }
#pragma unroll
    for (int i = 0; i < 4; i++) {
        float4 vv = make_float4(acc[i][0], acc[i][1], acc[i][2], acc[i][3]);
        *(float4*)&out[((long)b * 128 + o0 + i) * NP + n0 + nl] = vv;
    }
}

extern "C" void kernel_launch(void* const* d_in, const int* in_sizes, int n_in,
                              void* d_out, int out_size, void* d_ws, size_t ws_size,
                              hipStream_t stream) {
    const float* x  = (const float*)d_in[0];
    const float* W1 = (const float*)d_in[1];
    const float* W2 = (const float*)d_in[2];
    const float* W3 = (const float*)d_in[3];
    const float* W4 = (const float*)d_in[4];
    const float* W5 = (const float*)d_in[5];
    const float* g1 = (const float*)d_in[6];
    const float* b1 = (const float*)d_in[7];
    const float* g2 = (const float*)d_in[8];
    const float* b2 = (const float*)d_in[9];
    const float* g3 = (const float*)d_in[10];
    const float* b3 = (const float*)d_in[11];
    const float* g4 = (const float*)d_in[12];
    const float* b4 = (const float*)d_in[13];
    float* out = (float*)d_out;
    float* ws  = (float*)d_ws;
    // ws layout (floats): p | r | mmax | mmin | xx | sums | XT
    float* p    = ws;
    float* r    = ws + 524288;
    float* mmax = ws + 1048576;
    float* mmin = ws + 1572864;
    float* xx   = ws + 2097152;
    float* sums = ws + 2113536;
    float* XT   = ws + 2113792;   // up to 8*2048*36 = 589824 floats
    hipMemsetAsync(sums, 0, 256 * sizeof(float), stream);

    // block 1 (C=9): plain prep
    prep_kernel<9, 12, 16><<<2048, 256, 0, stream>>>(x, 9L * NP, W1, p, r, xx, XT);
    knn_kernel<9, 12, 16><<<512, 512, 0, stream>>>(x, 9L * NP, p, r, xx, XT, mmax, mmin, sums);
    // F2 = finish1 (resid=null, out ch[0:32)) + prep2 (W2)
    fp_kernel<<<2048, 256, 0, stream>>>(mmax, mmin, sums, g1, b1, nullptr, out, W2, p, r, xx, XT);
    knn_kernel<32, 32, 36><<<512, 512, 0, stream>>>(out, 128L * NP, p, r, xx, XT, mmax, mmin, sums + 64);
    // F3 = finish2 (resid=x1, out ch[32:64)) + prep3 (W3)
    fp_kernel<<<2048, 256, 0, stream>>>(mmax, mmin, sums + 64, g2, b2, out, out + 32 * NP, W3, p, r, xx, XT);
    knn_kernel<32, 32, 36><<<512, 512, 0, stream>>>(out + 32 * NP, 128L * NP, p, r, xx, XT, mmax, mmin, sums + 128);
    // F4 = finish3 (resid=x2, out ch[64:96)) + prep4 (W4)
    fp_kernel<<<2048, 256, 0, stream>>>(mmax, mmin, sums + 128, g3, b3, out + 32 * NP, out + 64 * NP, W4, p, r, xx, XT);
    knn_kernel<32, 32, 36><<<512, 512, 0, stream>>>(out + 64 * NP, 128L * NP, p, r, xx, XT, mmax, mmin, sums + 192);
    // final GEMM with finish4 fused (channels 96..128 computed inline)
    final_gemm<<<512, 256, 0, stream>>>(W5, out, mmax, mmin, sums + 192, g4, b4);
}

// Round 13
// 589.817 us; speedup vs baseline: 1.2845x; 1.2845x over previous
//
#include <hip/hip_runtime.h>
#include <stdint.h>

#define NP 2048
#define KNN 40
#define CAP 128          // candidate buffer per row (2 slots of 64, int — proven type)

__device__ __forceinline__ unsigned fOrd(float f) {
    unsigned u = __float_as_uint(f);
    return u ^ ((unsigned)((int)u >> 31) | 0x80000000u);
}
__device__ __forceinline__ unsigned long long dOrd(double d) {
    unsigned long long u = (unsigned long long)__double_as_longlong(d);
    return u ^ (((unsigned long long)((long long)u >> 63)) | 0x8000000000000000ull);
}

// ---------------------------------------------------------------------------
// prep: per point: xx = sum x^2 (fp32), p[o] = Wd[o,:]·x, r[o] = (Wc-Wd)[o,:]·x,
// XT[b][n][0..CP) = x (point-contiguous, zero-padded) + fp64 norm at offset CP
// (sequential c-order — must match refine's usage). Used only for block 1.
// ---------------------------------------------------------------------------
template<int C, int CP, int CPX>
__global__ void prep_kernel(const float* __restrict__ X, long bstride,
                            const float* __restrict__ W,
                            float* __restrict__ p, float* __restrict__ r,
                            float* __restrict__ xx, float* __restrict__ XT) {
    __shared__ float wdT[C][32];
    __shared__ float wrT[C][32];
    int tid = threadIdx.x;
    for (int i = tid; i < 32 * C; i += 256) {
        int o = i / C, c = i - o * C;
        float wd = W[o * 2 * C + c];
        float wc = W[o * 2 * C + C + c];
        wdT[c][o] = wd;
        wrT[c][o] = wc - wd;
    }
    __syncthreads();
    int lane = tid & 63;
    int o = lane & 31;
    int h = lane >> 5;
    int wv = tid >> 6;
    int flat = blockIdx.x * 8 + wv * 2 + h;   // 2048 wgs * 8 points = B*N
    int b = flat >> 11, n = flat & 2047;
    const float* Xb = X + (long)b * bstride + n;
    float pacc = 0.f, racc = 0.f, xxa = 0.f, xto = 0.f;
    double xxd = 0.0;
#pragma unroll
    for (int c = 0; c < C; c++) {
        float xv = Xb[(long)c * NP];
        pacc = fmaf(wdT[c][o], xv, pacc);
        racc = fmaf(wrT[c][o], xv, racc);
        xxa += xv * xv;
        xxd += (double)xv * (double)xv;       // sequential c order (refine-consistent)
        if (c == o) xto = xv;
    }
    long base = ((long)b * NP + n) * 32 + o;
    p[base] = pacc;
    r[base] = racc;
    long rowb = ((long)b * NP + n) * CPX;
    if (o < CP) XT[rowb + o] = (o < C) ? xto : 0.f;
    if (o == 0) {
        xx[b * NP + n] = xxa;
        *reinterpret_cast<double*>(&XT[rowb + CP]) = xxd;
    }
}

// ---------------------------------------------------------------------------
// knn: R11-PROVEN configuration (total 593us, knn 127us) — FINAL.
// R26 (4 rows/wave) RETIRED: VGPR 44->88 crossed the 64-VGPR occupancy
// boundary (m69), resident waves halved (occ 41->22%), knn 127->172us.
// The ILP<->occupancy trade is measured from both ends: TLP saturated
// (R22), 4-row ILP negative (R26), staging overlap negative (R23/R24),
// SALU offload negative (R19). 2 rows/wave + bitonic select + 36KB LDS
// + VGPR 44 is the empirical optimum of every lever explored.
// wg = 512 = 8 waves; each wave owns 2 rows; 1024 wgs (128 per batch).
// ---------------------------------------------------------------------------
template<int C, int CP, int CPX>
__global__ __launch_bounds__(512, 2)
void knn_kernel(const float* __restrict__ X, long bstride,
                const float* __restrict__ p, const float* __restrict__ r,
                const float* __restrict__ xx, const float* __restrict__ XT,
                float* __restrict__ mmax, float* __restrict__ mmin,
                float* __restrict__ sums) {
    // union region: xt[2][C*128] (distance phase)  OR  cand[16][CAP]+sel[16][KNN]
    constexpr int XT_FLOATS = 2 * C * 128;
    constexpr int CS_FLOATS = 16 * CAP + 16 * KNN;
    constexpr int UNI_FLOATS = (XT_FLOATS > CS_FLOATS) ? XT_FLOATS : CS_FLOATS;
    __shared__ __align__(16) float uni[UNI_FLOATS];
    __shared__ __align__(16) float xxt[256];
    __shared__ __align__(8) float qld[8][CP][2];   // [wave][c][rowA/rowB]
    __shared__ float S1loc[32], S2loc[32];
    int* candb = (int*)uni;               // valid after post-distance barrier
    int* selb  = (int*)uni + 16 * CAP;
    int tid = threadIdx.x;
    if (tid < 32) { S1loc[tid] = 0.f; S2loc[tid] = 0.f; }
    int lane = tid & 63;
    int wv = tid >> 6;                    // 0..7
    int half = lane >> 5;                 // which of the 2 staged tiles
    int l32 = lane & 31;
    int b = blockIdx.x >> 7;              // 128 wgs per batch
    int n0 = (blockIdx.x & 127) * 16;
    int nA = n0 + wv * 2, nB = nA + 1;
    int rowA = wv * 2, rowB = rowA + 1;   // 0..15
    const float* Xb = X + (long)b * bstride;
    const float* XTb = XT + (long)b * NP * CPX;
    long bNP = (long)b * NP;

    // queries -> LDS (wave-private rows; barrier below covers visibility)
    if (lane < CP) {
        qld[wv][lane][0] = XTb[(long)nA * CPX + lane];
        qld[wv][lane][1] = XTb[(long)nB * CPX + lane];
    }
    float xxnA = xx[bNP + nA];
    float xxnB = xx[bNP + nB];

    unsigned uA[16], uB[16];   // 16-bit keys packed 2/reg; slot 2*t2+s, s=j>>1
    for (int t2 = 0; t2 < 8; t2++) {
        __syncthreads();
        // stage tiles 2*t2 (->xt half 0) and 2*t2+1 (->half 1); R10 pattern
        for (int i = tid; i < C * 64; i += 512) {
            int c = i >> 6, g = i & 63;
            int tt = g >> 5, gg = g & 31;
            *(float4*)&uni[tt * (C * 128) + c * 128 + gg * 4] =
                *(const float4*)&Xb[(long)c * NP + (t2 * 2 + tt) * 128 + gg * 4];
        }
        if (tid < 256) xxt[tid] = xx[bNP + t2 * 256 + tid];
        __syncthreads();
        const float* xth = uni + half * (C * 128);
        float4 ia = make_float4(0.f, 0.f, 0.f, 0.f);
        float4 ib = make_float4(0.f, 0.f, 0.f, 0.f);
#pragma unroll
        for (int c = 0; c < C; c++) {
            float2 q = *(const float2*)&qld[wv][c][0];      // b64 broadcast
            float4 xv = *(const float4*)&xth[c * 128 + 4 * l32]; // ONE b128/c
            ia.x = fmaf(q.x, xv.x, ia.x);
            ia.y = fmaf(q.x, xv.y, ia.y);
            ia.z = fmaf(q.x, xv.z, ia.z);
            ia.w = fmaf(q.x, xv.w, ia.w);
            ib.x = fmaf(q.y, xv.x, ib.x);
            ib.y = fmaf(q.y, xv.y, ib.y);
            ib.z = fmaf(q.y, xv.z, ib.z);
            ib.w = fmaf(q.y, xv.w, ib.w);
        }
        float4 xm = *(const float4*)&xxt[half * 128 + 4 * l32];
        unsigned a0 = fOrd((xxnA - 2.0f * ia.x) + xm.x) >> 16;   // ref rounding
        unsigned a1 = fOrd((xxnA - 2.0f * ia.y) + xm.y) >> 16;
        unsigned a2 = fOrd((xxnA - 2.0f * ia.z) + xm.z) >> 16;
        unsigned a3 = fOrd((xxnA - 2.0f * ia.w) + xm.w) >> 16;
        unsigned b0 = fOrd((xxnB - 2.0f * ib.x) + xm.x) >> 16;
        unsigned b1 = fOrd((xxnB - 2.0f * ib.y) + xm.y) >> 16;
        unsigned b2_ = fOrd((xxnB - 2.0f * ib.z) + xm.z) >> 16;
        unsigned b3 = fOrd((xxnB - 2.0f * ib.w) + xm.w) >> 16;
        uA[2 * t2]     = (a1 << 16) | a0;
        uA[2 * t2 + 1] = (a3 << 16) | a2;
        uB[2 * t2]     = (b1 << 16) | b0;
        uB[2 * t2 + 1] = (b3 << 16) | b2_;
    }
    // lifetime switch: all waves done reading xt before cand/sel writes
    __syncthreads();

    unsigned long long lmlt = (1ull << lane) - 1ull;

    // hoist f64 self-norms (independent global loads, hide under select)
    double xxdA = *reinterpret_cast<const double*>(&XTb[(long)nA * CPX + CP]);
    double xxdB = *reinterpret_cast<const double*>(&XTb[(long)nB * CPX + CP]);

    // --- pass 1 select, BOTH rows: fixed 16-step bitwise rank-40 select ---
    unsigned vA = 0u, vB = 0u;
    for (int bit = 15; bit >= 0; bit--) {
        unsigned tA = vA | ((1u << bit) - 1u);
        unsigned tB = vB | ((1u << bit) - 1u);
        int cA = 0, cB = 0;
#pragma unroll
        for (int t = 0; t < 16; t++) {
            cA += __popcll(__ballot((uA[t] & 0xFFFFu) <= tA));
            cA += __popcll(__ballot((uA[t] >> 16) <= tA));
            cB += __popcll(__ballot((uB[t] & 0xFFFFu) <= tB));
            cB += __popcll(__ballot((uB[t] >> 16) <= tB));
        }
        if (cA < KNN) vA |= (1u << bit);
        if (cB < KNN) vB |= (1u << bit);
    }
    unsigned thrA = (vA > 0xFFFEu) ? 0xFFFFu : vA + 1u;   // +1 bucket (proven)
    unsigned thrB = (vB > 0xFFFEu) ? 0xFFFFu : vB + 1u;

    // --- candidate lists, BOTH rows (m = t2*256 + half*128 + 4*l32 + j) ---
    int baseA = 0, baseB = 0;
#pragma unroll
    for (int kk = 0; kk < 16; kk++) {
#pragma unroll
        for (int hh = 0; hh < 2; hh++) {
            unsigned kA = hh ? (uA[kk] >> 16) : (uA[kk] & 0xFFFFu);
            unsigned kB = hh ? (uB[kk] >> 16) : (uB[kk] & 0xFFFFu);
            int idx = (kk >> 1) * 256 + half * 128 + 4 * l32 + (kk & 1) * 2 + hh;
            bool pA = (kA <= thrA), pB = (kB <= thrB);
            unsigned long long mkA = __ballot(pA), mkB = __ballot(pB);
            if (pA) {
                int pos = baseA + __popcll(mkA & lmlt);
                if (pos < CAP) candb[rowA * CAP + pos] = idx;
            }
            if (pB) {
                int pos = baseB + __popcll(mkB & lmlt);
                if (pos < CAP) candb[rowB * CAP + pos] = idx;
            }
            baseA += __popcll(mkA);
            baseB += __popcll(mkB);
        }
    }
    int cntA = baseA < CAP ? baseA : CAP;
    int cntB = baseB < CAP ? baseB : CAP;

    // --- refine candidates in float64, BOTH rows (exact order preserved) ---
    unsigned long long keyA[CAP / 64], keyB[CAP / 64];
    int mixA[CAP / 64], mixB[CAP / 64];
#pragma unroll
    for (int s3 = 0; s3 < CAP / 64; s3++) {
        int slot = s3 * 64 + lane;
        keyA[s3] = ~0ull; mixA[s3] = 0;
        keyB[s3] = ~0ull; mixB[s3] = 0;
        if (slot < cntA) {
            int m = candb[rowA * CAP + slot] & (NP - 1);   // defensive mask
            mixA[s3] = m;
            const float* xmp = XTb + (long)m * CPX;
            double inner = 0.0;
#pragma unroll
            for (int g = 0; g < CP / 4; g++) {
                float4 v = *(const float4*)&xmp[g * 4];
                inner += (double)qld[wv][g * 4 + 0][0] * (double)v.x;
                inner += (double)qld[wv][g * 4 + 1][0] * (double)v.y;
                inner += (double)qld[wv][g * 4 + 2][0] * (double)v.z;
                inner += (double)qld[wv][g * 4 + 3][0] * (double)v.w;
            }
            double xxm = *reinterpret_cast<const double*>(&xmp[CP]);
            double dd = (xxdA - 2.0 * inner) + xxm;
            keyA[s3] = dOrd(dd);
        }
        if (slot < cntB) {
            int m = candb[rowB * CAP + slot] & (NP - 1);   // defensive mask
            mixB[s3] = m;
            const float* xmp = XTb + (long)m * CPX;
            double inner = 0.0;
#pragma unroll
            for (int g = 0; g < CP / 4; g++) {
                float4 v = *(const float4*)&xmp[g * 4];
                inner += (double)qld[wv][g * 4 + 0][1] * (double)v.x;
                inner += (double)qld[wv][g * 4 + 1][1] * (double)v.y;
                inner += (double)qld[wv][g * 4 + 2][1] * (double)v.z;
                inner += (double)qld[wv][g * 4 + 3][1] * (double)v.w;
            }
            double xxm = *reinterpret_cast<const double*>(&xmp[CP]);
            double dd = (xxdB - 2.0 * inner) + xxm;
            keyB[s3] = dOrd(dd);
        }
    }

    // --- R20: rank select via in-register bitonic sort by (key, idx) ---
    auto cex = [](unsigned long long& k, int& i, const int S, const bool keepmin) {
        unsigned long long pk = __shfl_xor(k, S);
        int pi = __shfl_xor(i, S);
        bool less = (k < pk) || (k == pk && i < pi);
        bool tp = (less != keepmin);
        k = tp ? pk : k;
        i = tp ? pi : i;
    };
    if (cntA <= 64 && cntB <= 64) {
        // 64-element ascending bitonic sort, slot0 only (21 stages)
#pragma unroll
        for (int kk2 = 1; kk2 <= 6; kk2++) {
            const int K = 1 << kk2;
#pragma unroll
            for (int ss = kk2 - 1; ss >= 0; ss--) {
                const int S = 1 << ss;
                bool asc0 = (K == 64) ? true : ((lane & K) == 0);
                bool km0 = ((lane & S) == 0) == asc0;
                cex(keyA[0], mixA[0], S, km0);
                cex(keyB[0], mixB[0], S, km0);
            }
        }
    } else {
        // 128-element ascending bitonic sort, 2 slots/lane (element j = s3*64+lane)
#pragma unroll
        for (int kk2 = 1; kk2 <= 6; kk2++) {
            const int K = 1 << kk2;
#pragma unroll
            for (int ss = kk2 - 1; ss >= 0; ss--) {
                const int S = 1 << ss;
                bool ascL = (lane & K) == 0;
                bool asc0 = (K == 64) ? true  : ascL;   // j&64 = 0 for slot0
                bool asc1 = (K == 64) ? false : ascL;   // j&64 = 64 for slot1
                bool km0 = ((lane & S) == 0) == asc0;
                bool km1 = ((lane & S) == 0) == asc1;
                cex(keyA[0], mixA[0], S, km0);
                cex(keyA[1], mixA[1], S, km1);
                cex(keyB[0], mixB[0], S, km0);
                cex(keyB[1], mixB[1], S, km1);
            }
        }
        // K=128 level. s=64: local exchange between slots (ascending: e0=min)
        {
            bool lA = (keyA[0] < keyA[1]) || (keyA[0] == keyA[1] && mixA[0] < mixA[1]);
            unsigned long long tk = keyA[0]; int ti = mixA[0];
            keyA[0] = lA ? keyA[0] : keyA[1];  mixA[0] = lA ? mixA[0] : mixA[1];
            keyA[1] = lA ? keyA[1] : tk;       mixA[1] = lA ? mixA[1] : ti;
            bool lB = (keyB[0] < keyB[1]) || (keyB[0] == keyB[1] && mixB[0] < mixB[1]);
            tk = keyB[0]; ti = mixB[0];
            keyB[0] = lB ? keyB[0] : keyB[1];  mixB[0] = lB ? mixB[0] : mixB[1];
            keyB[1] = lB ? keyB[1] : tk;       mixB[1] = lB ? mixB[1] : ti;
        }
        // s = 32..1, ascending everywhere (j&128 == 0)
#pragma unroll
        for (int ss = 5; ss >= 0; ss--) {
            const int S = 1 << ss;
            bool km = ((lane & S) == 0);
            cex(keyA[0], mixA[0], S, km);
            cex(keyA[1], mixA[1], S, km);
            cex(keyB[0], mixB[0], S, km);
            cex(keyB[1], mixB[1], S, km);
        }
    }
    // ranks 0..63 now live in slot0 by lane; emit the 40 smallest (key,idx).
    // Emission writes ALL 40 slots unconditionally -> sel needs no init.
    if (lane < KNN) {
        selb[rowA * KNN + lane] = mixA[0];
        selb[rowB * KNN + lane] = mixB[0];
    }

    // --- fused gather-reduce over the selected 40, BOTH rows ---
    {
        int o = lane & 31, h = lane >> 5;
        float s1A = 0.f, s2A = 0.f, s1B = 0.f, s2B = 0.f;
        float mxA = -__builtin_inff(), mnA = __builtin_inff();
        float mxB = -__builtin_inff(), mnB = __builtin_inff();
        const float* pb = p + bNP * 32 + o;
        for (int k = h * 20; k < h * 20 + 20; k++) {
            int mA = selb[rowA * KNN + k] & (NP - 1);   // defensive mask
            int mB = selb[rowB * KNN + k] & (NP - 1);
            float pvA = pb[(long)mA * 32];
            float pvB = pb[(long)mB * 32];
            s1A += pvA;
            s2A = fmaf(pvA, pvA, s2A);
            mxA = fmaxf(mxA, pvA);
            mnA = fminf(mnA, pvA);
            s1B += pvB;
            s2B = fmaf(pvB, pvB, s2B);
            mxB = fmaxf(mxB, pvB);
            mnB = fminf(mnB, pvB);
        }
        s1A += __shfl_xor(s1A, 32);
        s2A += __shfl_xor(s2A, 32);
        mxA = fmaxf(mxA, __shfl_xor(mxA, 32));
        mnA = fminf(mnA, __shfl_xor(mnA, 32));
        s1B += __shfl_xor(s1B, 32);
        s2B += __shfl_xor(s2B, 32);
        mxB = fmaxf(mxB, __shfl_xor(mxB, 32));
        mnB = fminf(mnB, __shfl_xor(mnB, 32));
        if (h == 0) {
            long bseA = (bNP + nA) * 32 + o;
            float qA = r[bseA];
            mmax[bseA] = mxA + qA;
            mmin[bseA] = mnA + qA;
            atomicAdd(&S1loc[o], s1A + 40.f * qA);
            atomicAdd(&S2loc[o], fmaf(2.f * qA, s1A, fmaf(40.f * qA, qA, s2A)));
            long bseB = (bNP + nB) * 32 + o;
            float qB = r[bseB];
            mmax[bseB] = mxB + qB;
            mmin[bseB] = mnB + qB;
            atomicAdd(&S1loc[o], s1B + 40.f * qB);
            atomicAdd(&S2loc[o], fmaf(2.f * qB, s1B, fmaf(40.f * qB, qB, s2B)));
        }
    }
    __syncthreads();
    if (tid < 32) {
        atomicAdd(&sums[tid], S1loc[tid]);
        atomicAdd(&sums[32 + tid], S2loc[tid]);
    }
}

// ---------------------------------------------------------------------------
// fp_kernel (R25): fused finish(k-1) + prep(k), C=32 blocks only.
// Phase 1 (c-fast, coalesced mmax/mmin): y_pre = leaky(sc*v+sh) -> LDS.
// Phase 2 (n-fast, 32B-chunked resid/out): y = y_pre + resid; write outb + LDS.
// Phase 3: prep math from LDS y (bit-identical to prep_kernel reading HBM).
// ---------------------------------------------------------------------------
__global__ __launch_bounds__(256)
void fp_kernel(const float* __restrict__ mmax, const float* __restrict__ mmin,
               const float* __restrict__ sums_prev,
               const float* __restrict__ g, const float* __restrict__ be,
               const float* __restrict__ resid, float* __restrict__ outb,
               const float* __restrict__ W,
               float* __restrict__ p, float* __restrict__ r,
               float* __restrict__ xx, float* __restrict__ XT) {
    constexpr int C = 32, CP = 32, CPX = 36;
    __shared__ float wdT[C][32];
    __shared__ float wrT[C][32];
    __shared__ float yb[8][33];               // +1 pad: phase-2 bank spread
    int tid = threadIdx.x;
    for (int i = tid; i < 32 * C; i += 256) {
        int o = i / C, c = i - o * C;
        float wd = W[o * 2 * C + c];
        float wc = W[o * 2 * C + C + c];
        wdT[c][o] = wd;
        wrT[c][o] = wc - wd;
    }
    int flat0 = blockIdx.x * 8;               // 8 points per block
    int b = flat0 >> 11;
    int nb = flat0 & 2047;
    long bNP = (long)b * NP;
    const float cntf = 655360.0f;             // B*N*K
    {   // phase 1: c-fast — mmax/mmin reads fully coalesced
        int pi = tid >> 5, c = tid & 31;
        int n = nb + pi;
        float mean = sums_prev[c] / cntf;
        float var = sums_prev[32 + c] / cntf - mean * mean;
        float sc = g[c] / sqrtf(var + 1e-5f);
        float sh = be[c] - mean * sc;
        long bse = (bNP + n) * 32 + c;
        float v = (sc >= 0.f) ? mmax[bse] : mmin[bse];
        float y = sc * v + sh;
        y = (y >= 0.f) ? y : 0.2f * y;        // leaky BEFORE resid (ref order)
        yb[pi][c] = y;
    }
    __syncthreads();
    {   // phase 2: n-fast — resid/outb in contiguous 32B chunks per channel
        int c = tid >> 3, ni = tid & 7;
        int n = nb + ni;
        long ob = ((long)b * 128 + c) * NP + n;
        float y = yb[ni][c];
        if (resid) y += resid[ob];
        outb[ob] = y;                         // next knn stages X from here
        yb[ni][c] = y;
    }
    __syncthreads();
    // phase 3: prep from LDS y (identical math/order to prep_kernel)
    int lane = tid & 63;
    int o = lane & 31;
    int h = lane >> 5;
    int wv = tid >> 6;
    int pt = wv * 2 + h;
    int n = nb + pt;
    float pacc = 0.f, racc = 0.f, xxa = 0.f, xto = 0.f;
    double xxd = 0.0;
#pragma unroll
    for (int c = 0; c < C; c++) {
        float xv = yb[pt][c];
        pacc = fmaf(wdT[c][o], xv, pacc);
        racc = fmaf(wrT[c][o], xv, racc);
        xxa += xv * xv;
        xxd += (double)xv * (double)xv;       // sequential c order (refine-consistent)
        if (c == o) xto = xv;
    }
    long base = (bNP + n) * 32 + o;
    p[base] = pacc;
    r[base] = racc;
    long rowb = (bNP + n) * CPX;
    XT[rowb + o] = xto;                       // o < CP(=32) always; o<C always
    if (o == 0) {
        xx[bNP + n] = xxa;
        *reinterpret_cast<double*>(&XT[rowb + CP]) = xxd;
    }
}

// ---------------------------------------------------------------------------
// final in-place GEMM on d_out with finish4 FUSED for channels 96..128
// ---------------------------------------------------------------------------
__global__ void final_gemm(const float* __restrict__ W5, float* __restrict__ out,
                           const float* __restrict__ mmax, const float* __restrict__ mmin,
                           const float* __restrict__ sums4,
                           const float* __restrict__ g4, const float* __restrict__ be4) {
    __shared__ __align__(16) float catL[128][32];
    int b = blockIdx.x >> 6;
    int n0 = (blockIdx.x & 63) * 32;
    int tid = threadIdx.x;
    const float cntf = 655360.0f;
    long bNP = (long)b * NP;
    for (int i = tid; i < 128 * 32; i += 256) {
        int c = i >> 5, nn = i & 31;
        float val;
        if (c < 96) {
            val = out[((long)b * 128 + c) * NP + n0 + nn];
        } else {
            int o = c - 96;                    // inline finish4
            float mean = sums4[o] / cntf;
            float var = sums4[32 + o] / cntf - mean * mean;
            float sc = g4[o] / sqrtf(var + 1e-5f);
            float sh = be4[o] - mean * sc;
            long bse = (bNP + n0 + nn) * 32 + o;
            float v = (sc >= 0.f) ? mmax[bse] : mmin[bse];
            float y = sc * v + sh;
            y = (y >= 0.f) ? y : 0.2f * y;
            y += out[((long)b * 128 + 64 + o) * NP + n0 + nn];   // resid = x3
            val = y;
        }
        catL[c][nn] = val;
    }
    __syncthreads();
    int og = tid >> 3, ng = tid & 7;
    int o0 = og * 4, nl = ng * 4;
    float acc[4][4] = {};
    for (int c = 0; c < 128; c++) {
        float4 cv = *(const float4*)&catL[c][nl];
#pragma unroll
        for (int i = 0; i < 4; i++) {
            float w = W5[(o0 + i) * 128 + c];
            acc[i][0] = fmaf(w, cv.x, acc[i][0]);
            acc[i][1] = fmaf(w, cv.y, acc[i][1]);
            acc[i][2] = fmaf(w, cv.z, acc[i][2]);
            acc[i][3] = fmaf(w, cv.w, acc[i][3]);
        }
    }
#pragma unroll
    for (int i = 0; i < 4; i++) {
        float4 vv = make_float4(acc[i][0], acc[i][1], acc[i][2], acc[i][3]);
        *(float4*)&out[((long)b * 128 + o0 + i) * NP + n0 + nl] = vv;
    }
}

extern "C" void kernel_launch(void* const* d_in, const int* in_sizes, int n_in,
                              void* d_out, int out_size, void* d_ws, size_t ws_size,
                              hipStream_t stream) {
    const float* x  = (const float*)d_in[0];
    const float* W1 = (const float*)d_in[1];
    const float* W2 = (const float*)d_in[2];
    const float* W3 = (const float*)d_in[3];
    const float* W4 = (const float*)d_in[4];
    const float* W5 = (const float*)d_in[5];
    const float* g1 = (const float*)d_in[6];
    const float* b1 = (const float*)d_in[7];
    const float* g2 = (const float*)d_in[8];
    const float* b2 = (const float*)d_in[9];
    const float* g3 = (const float*)d_in[10];
    const float* b3 = (const float*)d_in[11];
    const float* g4 = (const float*)d_in[12];
    const float* b4 = (const float*)d_in[13];
    float* out = (float*)d_out;
    float* ws  = (float*)d_ws;
    // ws layout (floats): p | r | mmax | mmin | xx | sums | XT
    float* p    = ws;
    float* r    = ws + 524288;
    float* mmax = ws + 1048576;
    float* mmin = ws + 1572864;
    float* xx   = ws + 2097152;
    float* sums = ws + 2113536;
    float* XT   = ws + 2113792;   // up to 8*2048*36 = 589824 floats
    hipMemsetAsync(sums, 0, 256 * sizeof(float), stream);

    // block 1 (C=9): plain prep
    prep_kernel<9, 12, 16><<<2048, 256, 0, stream>>>(x, 9L * NP, W1, p, r, xx, XT);
    knn_kernel<9, 12, 16><<<1024, 512, 0, stream>>>(x, 9L * NP, p, r, xx, XT, mmax, mmin, sums);
    // F2 = finish1 (resid=null, out ch[0:32)) + prep2 (W2)
    fp_kernel<<<2048, 256, 0, stream>>>(mmax, mmin, sums, g1, b1, nullptr, out, W2, p, r, xx, XT);
    knn_kernel<32, 32, 36><<<1024, 512, 0, stream>>>(out, 128L * NP, p, r, xx, XT, mmax, mmin, sums + 64);
    // F3 = finish2 (resid=x1, out ch[32:64)) + prep3 (W3)
    fp_kernel<<<2048, 256, 0, stream>>>(mmax, mmin, sums + 64, g2, b2, out, out + 32 * NP, W3, p, r, xx, XT);
    knn_kernel<32, 32, 36><<<1024, 512, 0, stream>>>(out + 32 * NP, 128L * NP, p, r, xx, XT, mmax, mmin, sums + 128);
    // F4 = finish3 (resid=x2, out ch[64:96)) + prep4 (W4)
    fp_kernel<<<2048, 256, 0, stream>>>(mmax, mmin, sums + 128, g3, b3, out + 32 * NP, out + 64 * NP, W4, p, r, xx, XT);
    knn_kernel<32, 32, 36><<<1024, 512, 0, stream>>>(out + 64 * NP, 128L * NP, p, r, xx, XT, mmax, mmin, sums + 192);
    // final GEMM with finish4 fused (channels 96..128 computed inline)
    final_gemm<<<512, 256, 0, stream>>>(W5, out, mmax, mmin, sums + 192, g4, b4);
}